// Round 8
// baseline (4067.912 us; speedup 1.0000x reference)
//
#include <hip/hip_runtime.h>

// Fused SpikingDenseLayer: B=256, T=100, F=K=1024, U=1024.
// One block = one (batch b, 128-wide u-tile), 256 threads = 4 waves.
// v9 = scalar-pipe A + LDS W (replaces the v5 all-LDS / v6-v8 VMEM-W line):
//  * v5 (best so far, 630 us) is LDS-instruction-throughput bound: 7 A-reads
//    + 4 W-reads per 2-k wave-iter ~= 90 CU-LDS cyc -> 614 us model, 630
//    measured. 7+4 is minimal for any all-LDS mapping -> A must leave LDS.
//  * New ownership: wave w owns t-rows [25w, 25w+25); lane owns u = 2*lane
//    + {0,1}. A[t][k] is then WAVE-UNIFORM -> lives in SGPRs via
//    s_load_dwordx2 on the scalar pipe (readfirstlane makes uniformity
//    provable). v_fmac v_acc, s_a, v_w: zero VALU or LDS cost for A.
//  * Per 2-k iter: LDS = 2 x ds_read_b64 (W, stride-1, conflict-free)
//    = 12 cyc (was 90); VALU = 100 pure FMAs; 25 s_loads on scalar pipe.
//    FMA issue floor (341 us) becomes the binding resource.
//  * W staged via global_load_lds (v5's verified slot map), double-buffered
//    (2 x 8 KB inside the Cs region); barrier drain covered by ~1600 FMA cyc.
//  * No padded rows, no tail branch: 100 rows = 4 waves x 25 exactly.
// Per-output FMA chain k-ascending with the same expression forms as the
// passing v5 -> currents bitwise identical; scan math unchanged.

#define UN 128              // u-columns per block
#define BK 16               // k-slice staged per buffer
#define CS 132              // Cs row stride in floats (128 + 4)
#define RPW 25              // t-rows per wave
#define TMAX 100

__device__ __forceinline__ void gload_lds16(const float* g, float* l) {
    __builtin_amdgcn_global_load_lds(
        (const __attribute__((address_space(1))) void*)g,
        (__attribute__((address_space(3))) void*)l,
        16, 0, 0);
}

__global__ __launch_bounds__(256) void fused_snn(
    const float* __restrict__ x,     // [B,T,F]
    const float* __restrict__ W,     // [F,U]
    const float* __restrict__ bias,  // [U]
    float* __restrict__ spikes,      // [B,T,U]
    float* __restrict__ counts,      // [B,U]
    int B, int T, int F, int U)
{
    // smem: Ws double-buffer (2 x 2048 floats = 16 KB) during GEMM; whole
    // region reused as Cs[50][132] (26.4 KB) for the chunked scan.
    __shared__ __align__(16) float smem[50 * CS];
    float* Ws0 = smem;           // [16][128] linear
    float* Ws1 = smem + 2048;    // [16][128] linear

    const int tid  = threadIdx.x;
    const int lane = tid & 63;
    const int wv   = __builtin_amdgcn_readfirstlane(tid >> 6);   // wave 0..3
    const int u0   = blockIdx.x * UN;
    const int b    = blockIdx.y;

    float2 acc[RPW];
    #pragma unroll
    for (int r = 0; r < RPW; ++r) { acc[r].x = 0.f; acc[r].y = 0.f; }

    // Wave-uniform x base: rows [25*wv, 25*wv+25) of batch b.
    const float* xw = x + (size_t)b * T * F + (size_t)(wv * RPW) * F;

    // W staging (v5's verified map): slot tid -> row tid>>5, col (tid&31)*4;
    // rows +8 at slot 256+tid. LDS dest = slot*16 B (linear).
    const float* gw0 = W + (size_t)(tid >> 5) * U + u0 + (tid & 31) * 4;
    const float* gw1 = W + (size_t)(8 + (tid >> 5)) * U + u0 + (tid & 31) * 4;
    const int lw0 = tid * 4;
    const int lw1 = (256 + tid) * 4;

#define STAGE(buf, kof)                                        \
    do {                                                       \
        gload_lds16(gw0 + (size_t)(kof) * U, (buf) + lw0);     \
        gload_lds16(gw1 + (size_t)(kof) * U, (buf) + lw1);     \
    } while (0)

#define COMPUTE(buf, k0b)                                                  \
    do {                                                                   \
        const float* wp = (buf) + 2 * lane;                                \
        _Pragma("unroll 1")                                                \
        for (int kk = 0; kk < BK; kk += 2) {                               \
            const float* sx = xw + (k0b) + kk;      /* wave-uniform */     \
            float2 w0 = *(const float2*)(wp + kk * UN);                    \
            float2 w1 = *(const float2*)(wp + (kk + 1) * UN);              \
            _Pragma("unroll")                                              \
            for (int r = 0; r < RPW; ++r) {                                \
                float2 a = *(const float2*)(sx + (size_t)r * F);           \
                acc[r].x += a.x * w0.x;  acc[r].y += a.x * w0.y;           \
                acc[r].x += a.y * w1.x;  acc[r].y += a.y * w1.y;           \
            }                                                              \
        }                                                                  \
    } while (0)

    // prologue: fill buffer 0
    STAGE(Ws0, 0);
    __syncthreads();   // auto vmcnt(0): Ws0 visible

    #pragma unroll 1
    for (int k0 = 0; k0 < F; k0 += 2 * BK) {
        STAGE(Ws1, k0 + BK);                  // async: next tile into Ws1
        COMPUTE(Ws0, k0);
        __syncthreads();                      // drains STAGE, readers done
        if (k0 + 2 * BK < F) STAGE(Ws0, k0 + 2 * BK);
        COMPUTE(Ws1, k0 + BK);
        __syncthreads();
    }

#undef STAGE
#undef COMPUTE

    // ---- bias (per-lane float2 for u = {2*lane, 2*lane+1}) ----
    float2 b2 = *(const float2*)(bias + u0 + 2 * lane);

    // ---- chunked dump + LIF scan (2 x 50 t-rows) ----
    float vv = 0.f, cnt = 0.f;
    float* sp = spikes + (size_t)b * T * U + u0 + tid;   // used when tid<UN

    #pragma unroll
    for (int c = 0; c < 2; ++c) {
        if ((wv >> 1) == c) {                 // waves 2c, 2c+1 own this chunk
            const int rbase = (wv & 1) * RPW;
            #pragma unroll
            for (int r = 0; r < RPW; ++r) {
                float2 d;
                d.x = acc[r].x + b2.x;
                d.y = acc[r].y + b2.y;
                *(float2*)(smem + (rbase + r) * CS + 2 * lane) = d;
            }
        }
        __syncthreads();
        if (tid < UN) {
#pragma clang fp contract(off)
            // rounding matches numpy elementwise exactly:
            // v = 0.25*v + round(0.75*c); spike = v > 1.0; v -= spike.
            for (int r = 0; r < 50; ++r) {
                float cval = smem[r * CS + tid];
                vv = 0.25f * vv + 0.75f * cval;
                float s = (vv > 1.0f) ? 1.0f : 0.0f;
                vv -= s;
                cnt += s;
                sp[(size_t)(c * 50 + r) * U] = s;
            }
        }
        __syncthreads();   // scan done before chunk 1 overwrites Cs
    }
    if (tid < UN) counts[(size_t)b * U + u0 + tid] = cnt;
}

extern "C" void kernel_launch(void* const* d_in, const int* in_sizes, int n_in,
                              void* d_out, int out_size, void* d_ws, size_t ws_size,
                              hipStream_t stream) {
    const float* x    = (const float*)d_in[0];  // [B,T,F]
    const float* kern = (const float*)d_in[1];  // [F,U]
    const float* bias = (const float*)d_in[2];  // [U]
    float* out = (float*)d_out;

    const int U = in_sizes[2];                 // 1024
    const int F = in_sizes[1] / U;             // 1024
    const int R = in_sizes[0] / F;             // B*T = 25600
    const int B = out_size / U - R;            // 256
    const int T = R / B;                       // 100

    float* spikes = out;
    float* counts = out + (size_t)R * U;

    dim3 grid(U / UN, B);                      // (8, 256)
    fused_snn<<<grid, 256, 0, stream>>>(x, kern, bias, spikes, counts,
                                        B, T, F, U);
}

// Round 9
// 764.611 us; speedup vs baseline: 5.3202x; 5.3202x over previous
//
#include <hip/hip_runtime.h>

// Fused SpikingDenseLayer: B=256, T=100, F=K=1024, U=1024.
// One block = one (batch b, 256-wide u-tile), 256 threads = 4 waves.
// v10 = v5 (best verified, 630 us) with a wider 7x16 micro-tile:
//  * v5 is LDS-pipe bound: 7xb64 + 4xb128 = 90 LDS-cyc per 224 VALU-cyc
//    (model 614 us, measured 630). LDS cost scales as 8(t+u) bytes per
//    2tu FMAs -> widen u_per 8->16 (u-block 256): 138 LDS-cyc per 448
//    VALU-cyc, total LDS time 614 -> 472 us. Blocks halve (1024): half
//    the barriers, half the A re-fetch.
//  * acc[7][16] = 112 VGPR; body keeps peak ~160 (a[7] + one k's B regs
//    at a time), kk loop rolled (v4 spill lesson), NO launch_bounds
//    min-waves arg (measured hipcc cap ~= 256/arg would force a spill).
//    Spill tripwire: WRITE_SIZE must stay exactly 103424 KB.
//  * staging via global_load_lds (16B), linear layouts, v5's verified
//    slot maps (A identical; W extended to [16][256]).
//  * tail rows t=96..99 wave-uniform on wave 0 (tg=tid>>4: wave 0 owns
//    tg 0..3); exactly 100 t-rows issued.
// Per-output FMA chain k-ascending, same expression forms as passing v5
// -> currents bitwise identical; LIF scan math unchanged.

#define UN 256              // u-columns per block
#define BK 16               // k-slice staged per buffer
#define CSS 264             // Cs row stride in floats (256 + 8)
#define CHUNK 25            // t-rows per scan chunk (4 chunks)
#define TMAX 100

__device__ __forceinline__ void gload_lds16(const float* g, float* l) {
    __builtin_amdgcn_global_load_lds(
        (const __attribute__((address_space(1))) void*)g,
        (__attribute__((address_space(3))) void*)l,
        16, 0, 0);
}

__global__ __launch_bounds__(256) void fused_snn(
    const float* __restrict__ x,     // [B,T,F]
    const float* __restrict__ W,     // [F,U]
    const float* __restrict__ bias,  // [U]
    float* __restrict__ spikes,      // [B,T,U]
    float* __restrict__ counts,      // [B,U]
    int B, int T, int F, int U)
{
    // GEMM phase: As dbuf 2x1600 + Ws dbuf 2x4096 = 11392 floats (45.6 KB).
    // Scan phase reuses the region as Cs[25][264] (6600 floats).
    __shared__ __align__(16) float smem[11392];
    float* As0 = smem;            // [100][16] linear
    float* As1 = smem + 1600;
    float* Ws0 = smem + 3200;     // [16][256] linear
    float* Ws1 = smem + 7296;

    const int tid = threadIdx.x;
    const int tg  = tid >> 4;     // 0..15 -> t = i*16 + tg (wave-uniform tail)
    const int ug  = tid & 15;     // 0..15 -> u = ug*8+j / 128+ug*8+(j-8)
    const int u0  = blockIdx.x * UN;
    const int b   = blockIdx.y;

    float acc[7][16];
    #pragma unroll
    for (int i = 0; i < 7; i++)
        #pragma unroll
        for (int j = 0; j < 16; j++) acc[i][j] = 0.f;

    const float* xb = x + (size_t)b * T * F;

    // A staging (v5 verified): 100 rows x 64 B = 400 slots; slot s -> row
    // s>>2, byte (s&3)*16; LDS dest = slot*16.
    const float* ga0 = xb + (size_t)(tid >> 2) * F + (tid & 3) * 4;
    const float* ga1 = xb + (size_t)(64 + (tid >> 2)) * F + (tid & 3) * 4;
    const int la0 = tid * 4;
    const int la1 = (256 + tid) * 4;
    const bool a1on = (tid < 144);           // slots 256..399
    const bool w0   = (tid < 64);            // wave 0 owns tail rows 96..99

    // W staging: 16 rows x 1024 B = 1024 slots; thread covers slots
    // tid + 256*r (r=0..3): row (tid>>6)+4r, col (tid&63)*4.
    const float* gwr = W + (size_t)(tid >> 6) * U + u0 + (tid & 63) * 4;
    const int lw = tid * 4;

#define STAGE(abuf, wbuf, kof)                                          \
    do {                                                                \
        gload_lds16(ga0 + (kof), (abuf) + la0);                         \
        if (a1on) gload_lds16(ga1 + (kof), (abuf) + la1);               \
        _Pragma("unroll")                                               \
        for (int r = 0; r < 4; r++)                                     \
            gload_lds16(gwr + (size_t)((kof) + 4 * r) * U,              \
                        (wbuf) + lw + r * 1024);                        \
    } while (0)

    // 16 FMAs: acc[i][*] += av * {r0,r1,r2,r3}
#define FMA16(i, av, r0, r1, r2, r3)                                    \
    do {                                                                \
        acc[i][0]  += (av) * r0.x;  acc[i][1]  += (av) * r0.y;          \
        acc[i][2]  += (av) * r0.z;  acc[i][3]  += (av) * r0.w;          \
        acc[i][4]  += (av) * r1.x;  acc[i][5]  += (av) * r1.y;          \
        acc[i][6]  += (av) * r1.z;  acc[i][7]  += (av) * r1.w;          \
        acc[i][8]  += (av) * r2.x;  acc[i][9]  += (av) * r2.y;          \
        acc[i][10] += (av) * r2.z;  acc[i][11] += (av) * r2.w;          \
        acc[i][12] += (av) * r3.x;  acc[i][13] += (av) * r3.y;          \
        acc[i][14] += (av) * r3.z;  acc[i][15] += (av) * r3.w;          \
    } while (0)

#define COMPUTE(abuf, wbuf)                                             \
    do {                                                                \
        const float* ap  = (abuf) + tg * 16;                            \
        const float* wpk = (wbuf) + ug * 8;                             \
        _Pragma("unroll 1")                                             \
        for (int kk = 0; kk < BK; kk += 2) {                            \
            float2 a0 = *(const float2*)(ap + 0 * 256 + kk);            \
            float2 a1 = *(const float2*)(ap + 1 * 256 + kk);            \
            float2 a2 = *(const float2*)(ap + 2 * 256 + kk);            \
            float2 a3 = *(const float2*)(ap + 3 * 256 + kk);            \
            float2 a4 = *(const float2*)(ap + 4 * 256 + kk);            \
            float2 a5 = *(const float2*)(ap + 5 * 256 + kk);            \
            float2 a6;                                                  \
            if (w0) a6 = *(const float2*)(ap + 6 * 256 + kk);           \
            {   /* k = kk */                                            \
                const float* wr = wpk + kk * 256;                       \
                float4 p0 = *(const float4*)(wr);                       \
                float4 p1 = *(const float4*)(wr + 4);                   \
                float4 p2 = *(const float4*)(wr + 128);                 \
                float4 p3 = *(const float4*)(wr + 132);                 \
                FMA16(0, a0.x, p0, p1, p2, p3);                         \
                FMA16(1, a1.x, p0, p1, p2, p3);                         \
                FMA16(2, a2.x, p0, p1, p2, p3);                         \
                FMA16(3, a3.x, p0, p1, p2, p3);                         \
                FMA16(4, a4.x, p0, p1, p2, p3);                         \
                FMA16(5, a5.x, p0, p1, p2, p3);                         \
                if (w0) { FMA16(6, a6.x, p0, p1, p2, p3); }             \
            }                                                           \
            {   /* k = kk+1 */                                          \
                const float* wr = wpk + (kk + 1) * 256;                 \
                float4 q0 = *(const float4*)(wr);                       \
                float4 q1 = *(const float4*)(wr + 4);                   \
                float4 q2 = *(const float4*)(wr + 128);                 \
                float4 q3 = *(const float4*)(wr + 132);                 \
                FMA16(0, a0.y, q0, q1, q2, q3);                         \
                FMA16(1, a1.y, q0, q1, q2, q3);                         \
                FMA16(2, a2.y, q0, q1, q2, q3);                         \
                FMA16(3, a3.y, q0, q1, q2, q3);                         \
                FMA16(4, a4.y, q0, q1, q2, q3);                         \
                FMA16(5, a5.y, q0, q1, q2, q3);                         \
                if (w0) { FMA16(6, a6.y, q0, q1, q2, q3); }             \
            }                                                           \
        }                                                               \
    } while (0)

    // prologue: fill buffer set 0
    STAGE(As0, Ws0, 0);
    __syncthreads();   // auto vmcnt(0): tile 0 visible

    #pragma unroll 1
    for (int k0 = 0; k0 < F; k0 += 2 * BK) {
        STAGE(As1, Ws1, k0 + BK);             // async: next tile
        COMPUTE(As0, Ws0);
        __syncthreads();                      // drains STAGE, readers done
        if (k0 + 2 * BK < F) STAGE(As0, Ws0, k0 + 2 * BK);
        COMPUTE(As1, Ws1);
        __syncthreads();
    }

#undef STAGE
#undef COMPUTE
#undef FMA16

    // ---- bias (16 per thread) ----
    float bb[16];
    {
        float4 b0 = *(const float4*)(bias + u0 + ug * 8);
        float4 b1 = *(const float4*)(bias + u0 + ug * 8 + 4);
        float4 b2 = *(const float4*)(bias + u0 + 128 + ug * 8);
        float4 b3 = *(const float4*)(bias + u0 + 128 + ug * 8 + 4);
        bb[0]=b0.x; bb[1]=b0.y; bb[2]=b0.z; bb[3]=b0.w;
        bb[4]=b1.x; bb[5]=b1.y; bb[6]=b1.z; bb[7]=b1.w;
        bb[8]=b2.x; bb[9]=b2.y; bb[10]=b2.z; bb[11]=b2.w;
        bb[12]=b3.x; bb[13]=b3.y; bb[14]=b3.z; bb[15]=b3.w;
    }

    // ---- chunked dump + LIF scan (4 x 25 t-rows; 256 u-cols) ----
    float vv = 0.f, cnt = 0.f;
    float* sp = spikes + (size_t)b * T * U + u0 + tid;

    #pragma unroll
    for (int c = 0; c < 4; c++) {
        #pragma unroll
        for (int i = 0; i < 7; i++) {
            const int t = i * 16 + tg;
            if (t >= c * CHUNK && t < c * CHUNK + CHUNK && t < TMAX) {
                const int r = t - c * CHUNK;
                float4 d0, d1, d2, d3;
                d0.x = acc[i][0]  + bb[0];  d0.y = acc[i][1]  + bb[1];
                d0.z = acc[i][2]  + bb[2];  d0.w = acc[i][3]  + bb[3];
                d1.x = acc[i][4]  + bb[4];  d1.y = acc[i][5]  + bb[5];
                d1.z = acc[i][6]  + bb[6];  d1.w = acc[i][7]  + bb[7];
                d2.x = acc[i][8]  + bb[8];  d2.y = acc[i][9]  + bb[9];
                d2.z = acc[i][10] + bb[10]; d2.w = acc[i][11] + bb[11];
                d3.x = acc[i][12] + bb[12]; d3.y = acc[i][13] + bb[13];
                d3.z = acc[i][14] + bb[14]; d3.w = acc[i][15] + bb[15];
                float* row = smem + r * CSS;
                *(float4*)(row + ug * 8)           = d0;
                *(float4*)(row + ug * 8 + 4)       = d1;
                *(float4*)(row + 128 + ug * 8)     = d2;
                *(float4*)(row + 128 + ug * 8 + 4) = d3;
            }
        }
        __syncthreads();
        {
#pragma clang fp contract(off)
            // rounding matches numpy elementwise exactly:
            // v = 0.25*v + round(0.75*c); spike = v > 1.0; v -= spike.
            for (int r = 0; r < CHUNK; r++) {
                float cval = smem[r * CSS + tid];
                vv = 0.25f * vv + 0.75f * cval;
                float s = (vv > 1.0f) ? 1.0f : 0.0f;
                vv -= s;
                cnt += s;
                sp[(size_t)(c * CHUNK + r) * U] = s;
            }
        }
        __syncthreads();   // scan done before next chunk overwrites Cs
    }
    counts[(size_t)b * U + u0 + tid] = cnt;
}

extern "C" void kernel_launch(void* const* d_in, const int* in_sizes, int n_in,
                              void* d_out, int out_size, void* d_ws, size_t ws_size,
                              hipStream_t stream) {
    const float* x    = (const float*)d_in[0];  // [B,T,F]
    const float* kern = (const float*)d_in[1];  // [F,U]
    const float* bias = (const float*)d_in[2];  // [U]
    float* out = (float*)d_out;

    const int U = in_sizes[2];                 // 1024
    const int F = in_sizes[1] / U;             // 1024
    const int R = in_sizes[0] / F;             // B*T = 25600
    const int B = out_size / U - R;            // 256
    const int T = R / B;                       // 100

    float* spikes = out;
    float* counts = out + (size_t)R * U;

    dim3 grid(U / UN, B);                      // (4, 256)
    fused_snn<<<grid, 256, 0, stream>>>(x, kern, bias, spikes, counts,
                                        B, T, F, U);
}

// Round 10
// 745.477 us; speedup vs baseline: 5.4568x; 1.0257x over previous
//
#include <hip/hip_runtime.h>

// Fused SpikingDenseLayer: B=256, T=100, F=K=1024, U=1024.
// One block = one (batch b, 256-wide u-tile), 256 threads = 4 waves.
// v11 = v10 with the W-read bank conflict fixed:
//  * v10 read W at ug*8 float offsets (32-float lane stride) -> bank =
//    (ug*8)%32 -> ug,ug+4,ug+8,ug+12 collide = 4-WAY conflict on every
//    ds_read_b128 (SQ_LDS_BANK_CONFLICT = 6.8e7 ~= 4 extra cyc x 16.8M
//    reads; LDS 194 cyc/iter vs 138 ideal; 730 us measured).
//  * Fix: thread owns u = {4ug, 64+4ug, 128+4ug, 192+4ug}+{0..3}; the four
//    b128 reads sit at base bank (4ug)%32 -> 2-way alias (ug vs ug+8) =
//    FREE (m136; v5 measured 0 with this stride). LDS back to 138 cyc/iter
//    -> model 471 us LDS / 382 us FMA.
//  * Everything else = v10: 7x16 acc, rolled kk (v4 spill lesson), no
//    launch_bounds min-waves arg, global_load_lds staging (A map verified
//    since v2; W [16][256] linear), tail rows wave-uniform on wave 0.
//    Spill tripwire: WRITE_SIZE must stay exactly 103424 KB.
// Per-output FMA chain k-ascending, same expression forms as passing
// v5/v10 -> currents bitwise identical; LIF scan math unchanged.

#define UN 256              // u-columns per block
#define BK 16               // k-slice staged per buffer
#define CSS 264             // Cs row stride in floats (256 + 8)
#define CHUNK 25            // t-rows per scan chunk (4 chunks)
#define TMAX 100

__device__ __forceinline__ void gload_lds16(const float* g, float* l) {
    __builtin_amdgcn_global_load_lds(
        (const __attribute__((address_space(1))) void*)g,
        (__attribute__((address_space(3))) void*)l,
        16, 0, 0);
}

__global__ __launch_bounds__(256) void fused_snn(
    const float* __restrict__ x,     // [B,T,F]
    const float* __restrict__ W,     // [F,U]
    const float* __restrict__ bias,  // [U]
    float* __restrict__ spikes,      // [B,T,U]
    float* __restrict__ counts,      // [B,U]
    int B, int T, int F, int U)
{
    // GEMM phase: As dbuf 2x1600 + Ws dbuf 2x4096 = 11392 floats (45.6 KB).
    // Scan phase reuses the region as Cs[25][264] (6600 floats).
    __shared__ __align__(16) float smem[11392];
    float* As0 = smem;            // [100][16] linear
    float* As1 = smem + 1600;
    float* Ws0 = smem + 3200;     // [16][256] linear
    float* Ws1 = smem + 7296;

    const int tid = threadIdx.x;
    const int tg  = tid >> 4;     // 0..15 -> t = i*16 + tg (wave-uniform tail)
    const int ug  = tid & 15;     // 0..15 -> u = 64*q + 4*ug + j
    const int u0  = blockIdx.x * UN;
    const int b   = blockIdx.y;

    float acc[7][16];
    #pragma unroll
    for (int i = 0; i < 7; i++)
        #pragma unroll
        for (int j = 0; j < 16; j++) acc[i][j] = 0.f;

    const float* xb = x + (size_t)b * T * F;

    // A staging (verified since v2): 100 rows x 64 B = 400 slots; slot s ->
    // row s>>2, byte (s&3)*16; LDS dest = slot*16.
    const float* ga0 = xb + (size_t)(tid >> 2) * F + (tid & 3) * 4;
    const float* ga1 = xb + (size_t)(64 + (tid >> 2)) * F + (tid & 3) * 4;
    const int la0 = tid * 4;
    const int la1 = (256 + tid) * 4;
    const bool a1on = (tid < 144);           // slots 256..399
    const bool w0   = (tid < 64);            // wave 0 owns tail rows 96..99

    // W staging: 16 rows x 1024 B = 1024 slots; thread covers slots
    // tid + 256*r (r=0..3): row (tid>>6)+4r, col (tid&63)*4.
    const float* gwr = W + (size_t)(tid >> 6) * U + u0 + (tid & 63) * 4;
    const int lw = tid * 4;

#define STAGE(abuf, wbuf, kof)                                          \
    do {                                                                \
        gload_lds16(ga0 + (kof), (abuf) + la0);                         \
        if (a1on) gload_lds16(ga1 + (kof), (abuf) + la1);               \
        _Pragma("unroll")                                               \
        for (int r = 0; r < 4; r++)                                     \
            gload_lds16(gwr + (size_t)((kof) + 4 * r) * U,              \
                        (wbuf) + lw + r * 1024);                        \
    } while (0)

    // 16 FMAs: acc[i][q*4+j] += av * rq[j]   (u = 64q + 4ug + j)
#define FMA16(i, av, r0, r1, r2, r3)                                    \
    do {                                                                \
        acc[i][0]  += (av) * r0.x;  acc[i][1]  += (av) * r0.y;          \
        acc[i][2]  += (av) * r0.z;  acc[i][3]  += (av) * r0.w;          \
        acc[i][4]  += (av) * r1.x;  acc[i][5]  += (av) * r1.y;          \
        acc[i][6]  += (av) * r1.z;  acc[i][7]  += (av) * r1.w;          \
        acc[i][8]  += (av) * r2.x;  acc[i][9]  += (av) * r2.y;          \
        acc[i][10] += (av) * r2.z;  acc[i][11] += (av) * r2.w;          \
        acc[i][12] += (av) * r3.x;  acc[i][13] += (av) * r3.y;          \
        acc[i][14] += (av) * r3.z;  acc[i][15] += (av) * r3.w;          \
    } while (0)

#define COMPUTE(abuf, wbuf)                                             \
    do {                                                                \
        const float* ap  = (abuf) + tg * 16;                            \
        const float* wpk = (wbuf) + ug * 4;                             \
        _Pragma("unroll 1")                                             \
        for (int kk = 0; kk < BK; kk += 2) {                            \
            float2 a0 = *(const float2*)(ap + 0 * 256 + kk);            \
            float2 a1 = *(const float2*)(ap + 1 * 256 + kk);            \
            float2 a2 = *(const float2*)(ap + 2 * 256 + kk);            \
            float2 a3 = *(const float2*)(ap + 3 * 256 + kk);            \
            float2 a4 = *(const float2*)(ap + 4 * 256 + kk);            \
            float2 a5 = *(const float2*)(ap + 5 * 256 + kk);            \
            float2 a6;                                                  \
            if (w0) a6 = *(const float2*)(ap + 6 * 256 + kk);           \
            {   /* k = kk */                                            \
                const float* wr = wpk + kk * 256;                       \
                float4 p0 = *(const float4*)(wr);                       \
                float4 p1 = *(const float4*)(wr + 64);                  \
                float4 p2 = *(const float4*)(wr + 128);                 \
                float4 p3 = *(const float4*)(wr + 192);                 \
                FMA16(0, a0.x, p0, p1, p2, p3);                         \
                FMA16(1, a1.x, p0, p1, p2, p3);                         \
                FMA16(2, a2.x, p0, p1, p2, p3);                         \
                FMA16(3, a3.x, p0, p1, p2, p3);                         \
                FMA16(4, a4.x, p0, p1, p2, p3);                         \
                FMA16(5, a5.x, p0, p1, p2, p3);                         \
                if (w0) { FMA16(6, a6.x, p0, p1, p2, p3); }             \
            }                                                           \
            {   /* k = kk+1 */                                          \
                const float* wr = wpk + (kk + 1) * 256;                 \
                float4 q0 = *(const float4*)(wr);                       \
                float4 q1 = *(const float4*)(wr + 64);                  \
                float4 q2 = *(const float4*)(wr + 128);                 \
                float4 q3 = *(const float4*)(wr + 192);                 \
                FMA16(0, a0.y, q0, q1, q2, q3);                         \
                FMA16(1, a1.y, q0, q1, q2, q3);                         \
                FMA16(2, a2.y, q0, q1, q2, q3);                         \
                FMA16(3, a3.y, q0, q1, q2, q3);                         \
                FMA16(4, a4.y, q0, q1, q2, q3);                         \
                FMA16(5, a5.y, q0, q1, q2, q3);                         \
                if (w0) { FMA16(6, a6.y, q0, q1, q2, q3); }             \
            }                                                           \
        }                                                               \
    } while (0)

    // prologue: fill buffer set 0
    STAGE(As0, Ws0, 0);
    __syncthreads();   // auto vmcnt(0): tile 0 visible

    #pragma unroll 1
    for (int k0 = 0; k0 < F; k0 += 2 * BK) {
        STAGE(As1, Ws1, k0 + BK);             // async: next tile
        COMPUTE(As0, Ws0);
        __syncthreads();                      // drains STAGE, readers done
        if (k0 + 2 * BK < F) STAGE(As0, Ws0, k0 + 2 * BK);
        COMPUTE(As1, Ws1);
        __syncthreads();
    }

#undef STAGE
#undef COMPUTE
#undef FMA16

    // ---- bias (16 per thread; u = 64q + 4ug + j) ----
    float bb[16];
    {
        float4 b0 = *(const float4*)(bias + u0 + 4 * ug);
        float4 b1 = *(const float4*)(bias + u0 + 64 + 4 * ug);
        float4 b2 = *(const float4*)(bias + u0 + 128 + 4 * ug);
        float4 b3 = *(const float4*)(bias + u0 + 192 + 4 * ug);
        bb[0]=b0.x; bb[1]=b0.y; bb[2]=b0.z; bb[3]=b0.w;
        bb[4]=b1.x; bb[5]=b1.y; bb[6]=b1.z; bb[7]=b1.w;
        bb[8]=b2.x; bb[9]=b2.y; bb[10]=b2.z; bb[11]=b2.w;
        bb[12]=b3.x; bb[13]=b3.y; bb[14]=b3.z; bb[15]=b3.w;
    }

    // ---- chunked dump + LIF scan (4 x 25 t-rows; 256 u-cols) ----
    float vv = 0.f, cnt = 0.f;
    float* sp = spikes + (size_t)b * T * U + u0 + tid;

    #pragma unroll
    for (int c = 0; c < 4; c++) {
        #pragma unroll
        for (int i = 0; i < 7; i++) {
            const int t = i * 16 + tg;
            if (t >= c * CHUNK && t < c * CHUNK + CHUNK && t < TMAX) {
                const int r = t - c * CHUNK;
                float4 d0, d1, d2, d3;
                d0.x = acc[i][0]  + bb[0];  d0.y = acc[i][1]  + bb[1];
                d0.z = acc[i][2]  + bb[2];  d0.w = acc[i][3]  + bb[3];
                d1.x = acc[i][4]  + bb[4];  d1.y = acc[i][5]  + bb[5];
                d1.z = acc[i][6]  + bb[6];  d1.w = acc[i][7]  + bb[7];
                d2.x = acc[i][8]  + bb[8];  d2.y = acc[i][9]  + bb[9];
                d2.z = acc[i][10] + bb[10]; d2.w = acc[i][11] + bb[11];
                d3.x = acc[i][12] + bb[12]; d3.y = acc[i][13] + bb[13];
                d3.z = acc[i][14] + bb[14]; d3.w = acc[i][15] + bb[15];
                float* row = smem + r * CSS;
                *(float4*)(row + 4 * ug)        = d0;
                *(float4*)(row + 64 + 4 * ug)   = d1;
                *(float4*)(row + 128 + 4 * ug)  = d2;
                *(float4*)(row + 192 + 4 * ug)  = d3;
            }
        }
        __syncthreads();
        {
#pragma clang fp contract(off)
            // rounding matches numpy elementwise exactly:
            // v = 0.25*v + round(0.75*c); spike = v > 1.0; v -= spike.
            for (int r = 0; r < CHUNK; r++) {
                float cval = smem[r * CSS + tid];
                vv = 0.25f * vv + 0.75f * cval;
                float s = (vv > 1.0f) ? 1.0f : 0.0f;
                vv -= s;
                cnt += s;
                sp[(size_t)(c * CHUNK + r) * U] = s;
            }
        }
        __syncthreads();   // scan done before next chunk overwrites Cs
    }
    counts[(size_t)b * U + u0 + tid] = cnt;
}

extern "C" void kernel_launch(void* const* d_in, const int* in_sizes, int n_in,
                              void* d_out, int out_size, void* d_ws, size_t ws_size,
                              hipStream_t stream) {
    const float* x    = (const float*)d_in[0];  // [B,T,F]
    const float* kern = (const float*)d_in[1];  // [F,U]
    const float* bias = (const float*)d_in[2];  // [U]
    float* out = (float*)d_out;

    const int U = in_sizes[2];                 // 1024
    const int F = in_sizes[1] / U;             // 1024
    const int R = in_sizes[0] / F;             // B*T = 25600
    const int B = out_size / U - R;            // 256
    const int T = R / B;                       // 100

    float* spikes = out;
    float* counts = out + (size_t)R * U;

    dim3 grid(U / UN, B);                      // (4, 256)
    fused_snn<<<grid, 256, 0, stream>>>(x, kern, bias, spikes, counts,
                                        B, T, F, U);
}